// Round 10
// baseline (26.515 us; speedup 1.0000x reference)
//
#include <hip/hip_runtime.h>
#include <hip/hip_bf16.h>

#define S 1024
#define BLK 256    // 4 waves; 16 blocks/batch -> 1024 blocks, 4/CU

// hinge term: relu(1 - sign(l_i-l_j)*(p_i-p_j)), tie dl==0 -> 1.
// Labels are integer-valued (masked to {0..49}), so dl is an exact integer
// and sign(dl) == clamp(dl,-1,1) == v_med3_f32: 1 instruction.
// 6 VALU/term: sub, sub, med3, fma, max, acc-add.
__device__ __forceinline__ float pair_term(float pi, float li, float pj, float lj) {
  float dp = pi - pj;
  float dl = li - lj;
  float c = fminf(fmaxf(dl, -1.0f), 1.0f);   // v_med3_f32 clamp idiom
  return fmaxf(fmaf(-c, dp, 1.0f), 0.0f);
}

// N4 float4-iterations starting at f4lo; all 4 regs valid. Compile-time trip.
template <int N4>
__device__ __forceinline__ void uni4(const float4* pl4, int f4lo,
                                     const float pj[4], const float lj[4],
                                     float acc[4]) {
#pragma unroll
  for (int t = 0; t < N4; ++t) {
    float4 q = pl4[f4lo + t];
#pragma unroll
    for (int r = 0; r < 4; ++r) {
      acc[r] += pair_term(q.x, q.y, pj[r], lj[r]);
      acc[r] += pair_term(q.z, q.w, pj[r], lj[r]);
    }
  }
}

// Staircase row R of the 256-wide group at gb: i in [gb+64R+off, +8) (4 f4).
// Reg R predicated (i<j), regs r>R fully valid, regs r<R excluded.
template <int R>
__device__ __forceinline__ void stair_t(const float4* pl4, int gb, int off,
                                        int lane, const float pj[4],
                                        const float lj[4], float acc[4]) {
  const int i0 = gb + 64 * R + off;
  const int j = gb + 64 * R + lane;
#pragma unroll
  for (int t = 0; t < 4; ++t) {
    float4 q = pl4[(i0 >> 1) + t];
    const int i = i0 + 2 * t;
    float ta = (i     < j) ? pair_term(q.x, q.y, pj[R], lj[R]) : 0.0f;
    float tb = (i + 1 < j) ? pair_term(q.z, q.w, pj[R], lj[R]) : 0.0f;
    acc[R] += ta + tb;
#pragma unroll
    for (int r = R + 1; r < 4; ++r) {
      acc[r] += pair_term(q.x, q.y, pj[r], lj[r]);
      acc[r] += pair_term(q.z, q.w, pj[r], lj[r]);
    }
  }
}

__device__ __forceinline__ void stair(const float4* pl4, int gb, int R, int off,
                                      int lane, const float pj[4],
                                      const float lj[4], float acc[4]) {
  switch (R) {  // wave-uniform
    case 0: stair_t<0>(pl4, gb, off, lane, pj, lj, acc); break;
    case 1: stair_t<1>(pl4, gb, off, lane, pj, lj, acc); break;
    case 2: stair_t<2>(pl4, gb, off, lane, pj, lj, acc); break;
    default: stair_t<3>(pl4, gb, off, lane, pj, lj, acc); break;
  }
}

// Body templated on group pair {GLO, 3-GLO}: all uniform-loop trips static.
// Slot s in 0..31: uniform f4 chunk [s*4*g, +4*g) of each group, plus
// staircase rows: g_hi row s>>3, g_lo row 3-(s>>3), offset (s&7)*8.
template <int GLO>
__device__ __forceinline__ float body(const float2* pl, const float4* pl4,
                                      const float* msk, int s, int lane) {
  constexpr int GHI = 3 - GLO;
  float pjl[4], ljl[4], mjl[4], pjh[4], ljh[4], mjh[4];
#pragma unroll
  for (int r = 0; r < 4; ++r) {
    int jl = GLO * 256 + r * 64 + lane;
    int jh = GHI * 256 + r * 64 + lane;
    float2 vl = pl[jl], vh = pl[jh];
    pjl[r] = vl.x; ljl[r] = vl.y; mjl[r] = msk[jl];
    pjh[r] = vh.x; ljh[r] = vh.y; mjh[r] = msk[jh];
  }

  float accl[4] = {0.f, 0.f, 0.f, 0.f};
  float acch[4] = {0.f, 0.f, 0.f, 0.f};

  if (GLO > 0) uni4<4 * GLO>(pl4, s * 4 * GLO, pjl, ljl, accl);
  uni4<4 * GHI>(pl4, s * 4 * GHI, pjh, ljh, acch);

  const int R = s >> 3;
  const int off = (s & 7) * 8;
  stair(pl4, GHI * 256, R, off, lane, pjh, ljh, acch);
  stair(pl4, GLO * 256, 3 - R, off, lane, pjl, ljl, accl);

  float wacc = 0.0f;
#pragma unroll
  for (int r = 0; r < 4; ++r) {
    wacc = fmaf(accl[r], mjl[r], wacc);
    wacc = fmaf(acch[r], mjh[r], wacc);
  }
  return wacc;
}

// Fused kernel. Compute body identical to round-8 k1. Epilogue: block partial
// published with a device-scope (agent) atomic store; ACQ_REL ticket counter;
// the block drawing the last ticket finalizes (fixed-order reduction ->
// deterministic result independent of which block runs it). Counter is never
// reset: (old & (nblocks-1)) == nblocks-1 fires exactly once per call for any
// starting value, since each call adds exactly nblocks (power of 2).
__global__ __launch_bounds__(BLK) void rank_fused_kernel(
    const float* __restrict__ preds,
    const float* __restrict__ labels,
    const int* __restrict__ lens,
    float* __restrict__ out,
    float* partial,
    unsigned int* counter,
    int B, int nblocks) {
  const int bid = blockIdx.x;
  const int b = bid >> 4;
  const int k = bid & 15;

  __shared__ float2 pl[S];
  __shared__ float msk[S];
  __shared__ float wsum[BLK / 64];
  __shared__ int lastflag;

  const float* pr = preds + (size_t)b * S;
  const float* lr = labels + (size_t)b * S;
  {
    const float4 pv = ((const float4*)pr)[threadIdx.x];
    const float4 lv = ((const float4*)lr)[threadIdx.x];
    const float pm[4] = {pv.x, pv.y, pv.z, pv.w};
    const float lm[4] = {lv.x, lv.y, lv.z, lv.w};
#pragma unroll
    for (int e = 0; e < 4; ++e) {
      float m = (lm[e] != -1.0f) ? 1.0f : 0.0f;
      pl[threadIdx.x * 4 + e] = make_float2(pm[e] * m, lm[e] * m);
      msk[threadIdx.x * 4 + e] = m;
    }
  }
  __syncthreads();

  const int wv = threadIdx.x >> 6;
  const int lane = threadIdx.x & 63;
  const int s = (k >> 1) * 4 + wv;
  const float4* pl4 = (const float4*)pl;

  float wacc = (k & 1) ? body<1>(pl, pl4, msk, s, lane)
                       : body<0>(pl, pl4, msk, s, lane);

  for (int offr = 32; offr > 0; offr >>= 1)
    wacc += __shfl_down(wacc, offr, 64);
  if (lane == 0) wsum[wv] = wacc;
  __syncthreads();

  if (threadIdx.x == 0) {
    float tot = (wsum[0] + wsum[1]) + (wsum[2] + wsum[3]);
    __hip_atomic_store(&partial[bid], tot, __ATOMIC_RELAXED,
                       __HIP_MEMORY_SCOPE_AGENT);
    unsigned int old = __hip_atomic_fetch_add(counter, 1u, __ATOMIC_ACQ_REL,
                                              __HIP_MEMORY_SCOPE_AGENT);
    lastflag = ((old & (unsigned)(nblocks - 1)) == (unsigned)(nblocks - 1));
  }
  __syncthreads();

  if (lastflag) {
    // 256 threads: thread t reads partials 4t..4t+3 (all of batch t>>2).
    const int t = threadIdx.x;
    float sum = 0.0f;
#pragma unroll
    for (int q = 0; q < 4; ++q)
      sum += __hip_atomic_load(&partial[t * 4 + q], __ATOMIC_RELAXED,
                               __HIP_MEMORY_SCOPE_AGENT);
    sum += __shfl_xor(sum, 1, 64);
    sum += __shfl_xor(sum, 2, 64);   // quad holds batch sum

    float norm = 0.0f, sents = 0.0f;
    if ((t & 3) == 0) {
      const int bb = t >> 2;         // 0..63 == B
      const int ln = lens[bb];
      const float len = (float)ln;
      norm = sum / (len * len);
      sents = (ln != 0) ? 1.0f : 0.0f;
    }
    for (int off = 32; off > 0; off >>= 1) {
      norm  += __shfl_down(norm, off, 64);
      sents += __shfl_down(sents, off, 64);
    }
    __shared__ float wn[BLK / 64], ws2[BLK / 64];
    if ((t & 63) == 0) { wn[t >> 6] = norm; ws2[t >> 6] = sents; }
    __syncthreads();
    if (t == 0) {
      float N  = (wn[0] + wn[1]) + (wn[2] + wn[3]);
      float Sn = (ws2[0] + ws2[1]) + (ws2[2] + ws2[3]);
      out[0] = N / Sn;
      out[1] = Sn;
    }
  }
}

extern "C" void kernel_launch(void* const* d_in, const int* in_sizes, int n_in,
                              void* d_out, int out_size, void* d_ws, size_t ws_size,
                              hipStream_t stream) {
  const float* preds  = (const float*)d_in[0];
  const float* labels = (const float*)d_in[1];
  const int*   lens   = (const int*)d_in[2];
  float* out = (float*)d_out;

  const int B = in_sizes[2];                  // 64
  const int nblocks = B * 16;                 // 1024 (power of 2)

  unsigned int* counter = (unsigned int*)d_ws;          // 4 B, never reset
  float* partial = (float*)((char*)d_ws + 256);         // nblocks floats

  rank_fused_kernel<<<dim3(nblocks), dim3(BLK), 0, stream>>>(
      preds, labels, lens, out, partial, counter, B, nblocks);
}

// Round 11
// 13.929 us; speedup vs baseline: 1.9036x; 1.9036x over previous
//
#include <hip/hip_runtime.h>
#include <hip/hip_bf16.h>

#define S 1024
#define BLK 256    // 4 waves; 16 blocks/batch -> 1024 blocks, 4/CU

// hinge term: relu(1 - sign(l_i-l_j)*(p_i-p_j)), tie dl==0 -> 1.
// Labels are integer-valued (masked to {0..49}), so dl is an exact integer
// and sign(dl) == clamp(dl,-1,1) == v_med3_f32: 1 instruction.
// 6 VALU/term: sub, sub, med3, fma, max, acc-add.
__device__ __forceinline__ float pair_term(float pi, float li, float pj, float lj) {
  float dp = pi - pj;
  float dl = li - lj;
  float c = fminf(fmaxf(dl, -1.0f), 1.0f);   // v_med3_f32 clamp idiom
  return fmaxf(fmaf(-c, dp, 1.0f), 0.0f);
}

// N4 float4-iterations starting at f4lo; all 4 regs valid. Compile-time trip.
template <int N4>
__device__ __forceinline__ void uni4(const float4* pl4, int f4lo,
                                     const float pj[4], const float lj[4],
                                     float acc[4]) {
#pragma unroll
  for (int t = 0; t < N4; ++t) {
    float4 q = pl4[f4lo + t];
#pragma unroll
    for (int r = 0; r < 4; ++r) {
      acc[r] += pair_term(q.x, q.y, pj[r], lj[r]);
      acc[r] += pair_term(q.z, q.w, pj[r], lj[r]);
    }
  }
}

// Staircase row R of the 256-wide group at gb: i in [gb+64R+off, +8) (4 f4).
// Reg R predicated (i<j), regs r>R fully valid, regs r<R excluded.
template <int R>
__device__ __forceinline__ void stair_t(const float4* pl4, int gb, int off,
                                        int lane, const float pj[4],
                                        const float lj[4], float acc[4]) {
  const int i0 = gb + 64 * R + off;
  const int j = gb + 64 * R + lane;
#pragma unroll
  for (int t = 0; t < 4; ++t) {
    float4 q = pl4[(i0 >> 1) + t];
    const int i = i0 + 2 * t;
    float ta = (i     < j) ? pair_term(q.x, q.y, pj[R], lj[R]) : 0.0f;
    float tb = (i + 1 < j) ? pair_term(q.z, q.w, pj[R], lj[R]) : 0.0f;
    acc[R] += ta + tb;
#pragma unroll
    for (int r = R + 1; r < 4; ++r) {
      acc[r] += pair_term(q.x, q.y, pj[r], lj[r]);
      acc[r] += pair_term(q.z, q.w, pj[r], lj[r]);
    }
  }
}

__device__ __forceinline__ void stair(const float4* pl4, int gb, int R, int off,
                                      int lane, const float pj[4],
                                      const float lj[4], float acc[4]) {
  switch (R) {  // wave-uniform
    case 0: stair_t<0>(pl4, gb, off, lane, pj, lj, acc); break;
    case 1: stair_t<1>(pl4, gb, off, lane, pj, lj, acc); break;
    case 2: stair_t<2>(pl4, gb, off, lane, pj, lj, acc); break;
    default: stair_t<3>(pl4, gb, off, lane, pj, lj, acc); break;
  }
}

// Body templated on group pair {GLO, 3-GLO}: all uniform-loop trips static.
// Slot s in 0..31: uniform f4 chunk [s*4*g, +4*g) of each group, plus
// staircase rows: g_hi row s>>3, g_lo row 3-(s>>3), offset (s&7)*8.
template <int GLO>
__device__ __forceinline__ float body(const float2* pl, const float4* pl4,
                                      const float* msk, int s, int lane) {
  constexpr int GHI = 3 - GLO;
  float pjl[4], ljl[4], mjl[4], pjh[4], ljh[4], mjh[4];
#pragma unroll
  for (int r = 0; r < 4; ++r) {
    int jl = GLO * 256 + r * 64 + lane;
    int jh = GHI * 256 + r * 64 + lane;
    float2 vl = pl[jl], vh = pl[jh];
    pjl[r] = vl.x; ljl[r] = vl.y; mjl[r] = msk[jl];
    pjh[r] = vh.x; ljh[r] = vh.y; mjh[r] = msk[jh];
  }

  float accl[4] = {0.f, 0.f, 0.f, 0.f};
  float acch[4] = {0.f, 0.f, 0.f, 0.f};

  if (GLO > 0) uni4<4 * GLO>(pl4, s * 4 * GLO, pjl, ljl, accl);
  uni4<4 * GHI>(pl4, s * 4 * GHI, pjh, ljh, acch);

  const int R = s >> 3;
  const int off = (s & 7) * 8;
  stair(pl4, GHI * 256, R, off, lane, pjh, ljh, acch);
  stair(pl4, GLO * 256, 3 - R, off, lane, pjl, ljl, accl);

  float wacc = 0.0f;
#pragma unroll
  for (int r = 0; r < 4; ++r) {
    wacc = fmaf(accl[r], mjl[r], wacc);
    wacc = fmaf(acch[r], mjh[r], wacc);
  }
  return wacc;
}

// Kernel 1 (identical to round-8 best): batch b = bid>>4, k = bid&15.
// P=k&1 -> pair {P,3-P}; slot s = (k>>1)*4 + wave (0..31).
__global__ __launch_bounds__(BLK) void rank_partial_kernel(
    const float* __restrict__ preds,
    const float* __restrict__ labels,
    float* __restrict__ partial) {
  const int bid = blockIdx.x;
  const int b = bid >> 4;
  const int k = bid & 15;

  __shared__ float2 pl[S];
  __shared__ float msk[S];
  __shared__ float wsum[BLK / 64];

  const float* pr = preds + (size_t)b * S;
  const float* lr = labels + (size_t)b * S;
  {
    const float4 pv = ((const float4*)pr)[threadIdx.x];
    const float4 lv = ((const float4*)lr)[threadIdx.x];
    const float pm[4] = {pv.x, pv.y, pv.z, pv.w};
    const float lm[4] = {lv.x, lv.y, lv.z, lv.w};
#pragma unroll
    for (int e = 0; e < 4; ++e) {
      float m = (lm[e] != -1.0f) ? 1.0f : 0.0f;
      pl[threadIdx.x * 4 + e] = make_float2(pm[e] * m, lm[e] * m);
      msk[threadIdx.x * 4 + e] = m;
    }
  }
  __syncthreads();

  const int wv = threadIdx.x >> 6;
  const int lane = threadIdx.x & 63;
  const int s = (k >> 1) * 4 + wv;
  const float4* pl4 = (const float4*)pl;

  float wacc = (k & 1) ? body<1>(pl, pl4, msk, s, lane)
                       : body<0>(pl, pl4, msk, s, lane);

  for (int offr = 32; offr > 0; offr >>= 1)
    wacc += __shfl_down(wacc, offr, 64);
  if (lane == 0) wsum[wv] = wacc;
  __syncthreads();
  if (threadIdx.x == 0)
    partial[bid] = wsum[0] + wsum[1] + wsum[2] + wsum[3];
}

// Kernel 2 (parallel): 256 threads. Thread t loads float4 partial[4t..4t+3]
// (all 16 partials of batch t>>2 across the quad), quad-shuffle to batch sum,
// normalize on quad leaders, deterministic block reduce.
__global__ __launch_bounds__(BLK) void rank_final_kernel(
    const float* __restrict__ partial,
    const int* __restrict__ lens,
    float* __restrict__ out,
    int B) {
  const int t = threadIdx.x;
  float s = 0.0f;
  if (t * 4 < B * 16) {
    float4 a = ((const float4*)partial)[t];
    s = (a.x + a.y) + (a.z + a.w);
  }
  s += __shfl_xor(s, 1, 64);
  s += __shfl_xor(s, 2, 64);   // all 4 lanes of quad hold batch sum

  float norm = 0.0f, sents = 0.0f;
  if ((t & 3) == 0 && (t >> 2) < B) {
    const int bb = t >> 2;
    const int ln = lens[bb];
    const float len = (float)ln;
    norm = s / (len * len);
    sents = (ln != 0) ? 1.0f : 0.0f;
  }
  for (int off = 32; off > 0; off >>= 1) {
    norm  += __shfl_down(norm, off, 64);
    sents += __shfl_down(sents, off, 64);
  }
  __shared__ float wn[BLK / 64], ws2[BLK / 64];
  if ((t & 63) == 0) { wn[t >> 6] = norm; ws2[t >> 6] = sents; }
  __syncthreads();
  if (t == 0) {
    float N  = (wn[0] + wn[1]) + (wn[2] + wn[3]);
    float Sn = (ws2[0] + ws2[1]) + (ws2[2] + ws2[3]);
    out[0] = N / Sn;
    out[1] = Sn;
  }
}

extern "C" void kernel_launch(void* const* d_in, const int* in_sizes, int n_in,
                              void* d_out, int out_size, void* d_ws, size_t ws_size,
                              hipStream_t stream) {
  const float* preds  = (const float*)d_in[0];
  const float* labels = (const float*)d_in[1];
  const int*   lens   = (const int*)d_in[2];
  float* out = (float*)d_out;

  const int B = in_sizes[2];                  // 64
  float* partial = (float*)d_ws;              // B * 16 floats

  rank_partial_kernel<<<dim3(B * 16), dim3(BLK), 0, stream>>>(preds, labels, partial);
  rank_final_kernel<<<dim3(1), dim3(BLK), 0, stream>>>(partial, lens, out, B);
}

// Round 12
// 13.714 us; speedup vs baseline: 1.9335x; 1.0157x over previous
//
#include <hip/hip_runtime.h>
#include <hip/hip_bf16.h>

#define S 1024
#define BLK 256    // 4 waves; 16 blocks/batch -> 1024 blocks, 4/CU

// hinge term: relu(1 - sign(l_i-l_j)*(p_i-p_j)), tie dl==0 -> 1.
// Labels are integer-valued (masked to {0..49}), so dl is an exact integer
// and sign(dl) == clamp(dl,-1,1) == v_med3_f32: 1 instruction.
// 6 VALU/term: sub, sub, med3, fma, max, acc-add.
__device__ __forceinline__ float pair_term(float pi, float li, float pj, float lj) {
  float dp = pi - pj;
  float dl = li - lj;
  float c = fminf(fmaxf(dl, -1.0f), 1.0f);   // v_med3_f32 clamp idiom
  return fmaxf(fmaf(-c, dp, 1.0f), 0.0f);
}

// N4 float4-iterations starting at f4lo; all 4 regs valid. Compile-time trip.
template <int N4>
__device__ __forceinline__ void uni4(const float4* pl4, int f4lo,
                                     const float pj[4], const float lj[4],
                                     float acc[4]) {
#pragma unroll
  for (int t = 0; t < N4; ++t) {
    float4 q = pl4[f4lo + t];
#pragma unroll
    for (int r = 0; r < 4; ++r) {
      acc[r] += pair_term(q.x, q.y, pj[r], lj[r]);
      acc[r] += pair_term(q.z, q.w, pj[r], lj[r]);
    }
  }
}

// Staircase row R of the 256-wide group at gb: i in [gb+64R+off, +8) (4 f4).
// Reg R predicated (i<j), regs r>R fully valid, regs r<R excluded.
template <int R>
__device__ __forceinline__ void stair_t(const float4* pl4, int gb, int off,
                                        int lane, const float pj[4],
                                        const float lj[4], float acc[4]) {
  const int i0 = gb + 64 * R + off;
  const int j = gb + 64 * R + lane;
#pragma unroll
  for (int t = 0; t < 4; ++t) {
    float4 q = pl4[(i0 >> 1) + t];
    const int i = i0 + 2 * t;
    float ta = (i     < j) ? pair_term(q.x, q.y, pj[R], lj[R]) : 0.0f;
    float tb = (i + 1 < j) ? pair_term(q.z, q.w, pj[R], lj[R]) : 0.0f;
    acc[R] += ta + tb;
#pragma unroll
    for (int r = R + 1; r < 4; ++r) {
      acc[r] += pair_term(q.x, q.y, pj[r], lj[r]);
      acc[r] += pair_term(q.z, q.w, pj[r], lj[r]);
    }
  }
}

__device__ __forceinline__ void stair(const float4* pl4, int gb, int R, int off,
                                      int lane, const float pj[4],
                                      const float lj[4], float acc[4]) {
  switch (R) {  // wave-uniform
    case 0: stair_t<0>(pl4, gb, off, lane, pj, lj, acc); break;
    case 1: stair_t<1>(pl4, gb, off, lane, pj, lj, acc); break;
    case 2: stair_t<2>(pl4, gb, off, lane, pj, lj, acc); break;
    default: stair_t<3>(pl4, gb, off, lane, pj, lj, acc); break;
  }
}

// Body templated on group pair {GLO, 3-GLO}: all uniform-loop trips static.
// Slot s in 0..31: uniform f4 chunk [s*4*g, +4*g) of each group, plus
// staircase rows: g_hi row s>>3, g_lo row 3-(s>>3), offset (s&7)*8.
template <int GLO>
__device__ __forceinline__ float body(const float2* pl, const float4* pl4,
                                      const float* msk, int s, int lane) {
  constexpr int GHI = 3 - GLO;
  float pjl[4], ljl[4], mjl[4], pjh[4], ljh[4], mjh[4];
#pragma unroll
  for (int r = 0; r < 4; ++r) {
    int jl = GLO * 256 + r * 64 + lane;
    int jh = GHI * 256 + r * 64 + lane;
    float2 vl = pl[jl], vh = pl[jh];
    pjl[r] = vl.x; ljl[r] = vl.y; mjl[r] = msk[jl];
    pjh[r] = vh.x; ljh[r] = vh.y; mjh[r] = msk[jh];
  }

  float accl[4] = {0.f, 0.f, 0.f, 0.f};
  float acch[4] = {0.f, 0.f, 0.f, 0.f};

  if (GLO > 0) uni4<4 * GLO>(pl4, s * 4 * GLO, pjl, ljl, accl);
  uni4<4 * GHI>(pl4, s * 4 * GHI, pjh, ljh, acch);

  const int R = s >> 3;
  const int off = (s & 7) * 8;
  stair(pl4, GHI * 256, R, off, lane, pjh, ljh, acch);
  stair(pl4, GLO * 256, 3 - R, off, lane, pjl, ljl, accl);

  float wacc = 0.0f;
#pragma unroll
  for (int r = 0; r < 4; ++r) {
    wacc = fmaf(accl[r], mjl[r], wacc);
    wacc = fmaf(acch[r], mjh[r], wacc);
  }
  return wacc;
}

// Kernel 1: batch b = bid>>4, k = bid&15. P=k&1 -> pair {P,3-P};
// slot s = (k>>1)*4 + wave (0..31). Every wave ~136 terms/lane, balanced.
__global__ __launch_bounds__(BLK) void rank_partial_kernel(
    const float* __restrict__ preds,
    const float* __restrict__ labels,
    float* __restrict__ partial) {
  const int bid = blockIdx.x;
  const int b = bid >> 4;
  const int k = bid & 15;

  __shared__ float2 pl[S];
  __shared__ float msk[S];
  __shared__ float wsum[BLK / 64];

  const float* pr = preds + (size_t)b * S;
  const float* lr = labels + (size_t)b * S;
  {
    const float4 pv = ((const float4*)pr)[threadIdx.x];
    const float4 lv = ((const float4*)lr)[threadIdx.x];
    const float pm[4] = {pv.x, pv.y, pv.z, pv.w};
    const float lm[4] = {lv.x, lv.y, lv.z, lv.w};
#pragma unroll
    for (int e = 0; e < 4; ++e) {
      float m = (lm[e] != -1.0f) ? 1.0f : 0.0f;
      pl[threadIdx.x * 4 + e] = make_float2(pm[e] * m, lm[e] * m);
      msk[threadIdx.x * 4 + e] = m;
    }
  }
  __syncthreads();

  const int wv = threadIdx.x >> 6;
  const int lane = threadIdx.x & 63;
  const int s = (k >> 1) * 4 + wv;
  const float4* pl4 = (const float4*)pl;

  float wacc = (k & 1) ? body<1>(pl, pl4, msk, s, lane)
                       : body<0>(pl, pl4, msk, s, lane);

  for (int offr = 32; offr > 0; offr >>= 1)
    wacc += __shfl_down(wacc, offr, 64);
  if (lane == 0) wsum[wv] = wacc;
  __syncthreads();
  if (threadIdx.x == 0)
    partial[bid] = wsum[0] + wsum[1] + wsum[2] + wsum[3];
}

// Kernel 2: one wave. Lane b sums its 16 partials (4 float4 loads).
__global__ __launch_bounds__(64) void rank_final_kernel(
    const float* __restrict__ partial,
    const int* __restrict__ lens,
    float* __restrict__ out,
    int B) {
  const int b = threadIdx.x;
  float norm = 0.0f, sents = 0.0f;
  if (b < B) {
    const float4* p4 = (const float4*)partial;
    float sum = 0.0f;
#pragma unroll
    for (int q = 0; q < 4; ++q) {
      float4 a = p4[b * 4 + q];
      sum += (a.x + a.y) + (a.z + a.w);
    }
    float len = (float)lens[b];
    norm = sum / (len * len);
    sents = (lens[b] != 0) ? 1.0f : 0.0f;
  }
  for (int off = 32; off > 0; off >>= 1) {
    norm  += __shfl_down(norm, off, 64);
    sents += __shfl_down(sents, off, 64);
  }
  if (threadIdx.x == 0) {
    out[0] = norm / sents;
    out[1] = sents;
  }
}

extern "C" void kernel_launch(void* const* d_in, const int* in_sizes, int n_in,
                              void* d_out, int out_size, void* d_ws, size_t ws_size,
                              hipStream_t stream) {
  const float* preds  = (const float*)d_in[0];
  const float* labels = (const float*)d_in[1];
  const int*   lens   = (const int*)d_in[2];
  float* out = (float*)d_out;

  const int B = in_sizes[2];                  // 64
  float* partial = (float*)d_ws;              // B * 16 floats

  rank_partial_kernel<<<dim3(B * 16), dim3(BLK), 0, stream>>>(preds, labels, partial);
  rank_final_kernel<<<dim3(1), dim3(64), 0, stream>>>(partial, lens, out, B);
}